// Round 4
// baseline (1034.871 us; speedup 1.0000x reference)
//
#include <hip/hip_runtime.h>
#include <hip/hip_bf16.h>

// ---------------------------------------------------------------------------
// GNN: hiddens = relu(gcn(x,W1,b1)); emb = gcn(hiddens,W2,b2);
// pred_i/j = <emb[r,y,:],emb[c,y,:]> at head y[r]/y[c].
//
// aggregate-then-transform: A_norm @ (H @ W) = (A_norm @ H) @ W.
// CSR build: count (int4 x4 edges) -> 3-phase scan -> fill (int2 x2 edges).
// agg: wave/node, 2x32-lane edge groups, float4 gathers 4-deep in flight,
//      writes bf16 hi/lo (split hoisted out of GEMM).
// GEMM: split-bf16 MFMA (C = Ah*Bh + Ah*Bl + Al*Bh, fp32 accumulate).
//   128x128 tile, 4 waves (2x2), wave tile 64x64 = 4x4 frags of 16x16x32.
//   BK=64 x 2 phases, 64KB LDS -> 2 blocks/CU. T14 async-stage: phase-1
//   global loads issued into regs BEFORE phase-0 compute (latency hidden
//   under ~96 MFMAs), ds_write after the barrier.
// ---------------------------------------------------------------------------

#define SCAN_SEG 512   // elements per scan block (256 threads x 2)

typedef short bf16x8 __attribute__((ext_vector_type(8)));   // 8 bf16 in 4 VGPRs
typedef float f32x4  __attribute__((ext_vector_type(4)));

__device__ __forceinline__ ushort f2bf(float x) {           // truncate: lo term catches residual
    return (ushort)(__float_as_uint(x) >> 16);
}
__device__ __forceinline__ float bf2f(ushort h) {
    return __uint_as_float(((unsigned)h) << 16);
}

__global__ void count_kernel(const int* __restrict__ dst, int* __restrict__ cnt, int E) {
    int i = (blockIdx.x * blockDim.x + threadIdx.x) * 4;
    if (i + 3 < E) {
        int4 d = *(const int4*)(dst + i);
        atomicAdd(&cnt[d.x], 1);
        atomicAdd(&cnt[d.y], 1);
        atomicAdd(&cnt[d.z], 1);
        atomicAdd(&cnt[d.w], 1);
    } else {
        for (; i < E; ++i) atomicAdd(&cnt[dst[i]], 1);
    }
}

// phase 1: per-block segment sums (coalesced)
__global__ __launch_bounds__(256) void blocksum_kernel(const int* __restrict__ cnt,
                                                       int* __restrict__ blocksum, int n) {
    __shared__ int red[4];
    int b = blockIdx.x, t = threadIdx.x;
    int i0 = b * SCAN_SEG + t;
    int s = 0;
    if (i0 < n) s += cnt[i0];
    if (i0 + 256 < n) s += cnt[i0 + 256];
#pragma unroll
    for (int off = 32; off >= 1; off >>= 1) s += __shfl_xor(s, off, 64);
    if ((t & 63) == 0) red[t >> 6] = s;
    __syncthreads();
    if (t == 0) blocksum[b] = red[0] + red[1] + red[2] + red[3];
}

// phase 2: exclusive scan of <=256 block sums in one small block
__global__ __launch_bounds__(256) void blockscan_kernel(const int* __restrict__ blocksum,
                                                        int* __restrict__ blockoff, int nb,
                                                        int* __restrict__ row_ptr, int n, int E) {
    __shared__ int s[256];
    int t = threadIdx.x;
    int v = (t < nb) ? blocksum[t] : 0;
    s[t] = v;
    __syncthreads();
    for (int off = 1; off < 256; off <<= 1) {
        int u = (t >= off) ? s[t - off] : 0;
        __syncthreads();
        s[t] += u;
        __syncthreads();
    }
    if (t < nb) blockoff[t] = s[t] - v;   // exclusive
    if (t == 0) row_ptr[n] = E;
}

// phase 3: per-block exclusive scan over its 512-elem segment -> row_ptr/cursor/dinv
__global__ __launch_bounds__(256) void csr_ptr_kernel(const int* __restrict__ cnt,
                                                      const int* __restrict__ blockoff,
                                                      int* __restrict__ row_ptr,
                                                      int* __restrict__ cursor,
                                                      float* __restrict__ dinv, int n) {
    __shared__ int s[256];
    int b = blockIdx.x, t = threadIdx.x;
    int i0 = b * SCAN_SEG + 2 * t;       // thread handles i0, i0+1
    int c0 = (i0     < n) ? cnt[i0]     : 0;
    int c1 = (i0 + 1 < n) ? cnt[i0 + 1] : 0;
    int pair = c0 + c1;
    s[t] = pair;
    __syncthreads();
    for (int off = 1; off < 256; off <<= 1) {
        int u = (t >= off) ? s[t - off] : 0;
        __syncthreads();
        s[t] += u;
        __syncthreads();
    }
    int excl = s[t] - pair + blockoff[b];
    if (i0 < n) {
        row_ptr[i0] = excl;
        cursor[i0]  = excl;
        dinv[i0]    = rsqrtf((float)(c0 + 1));
    }
    if (i0 + 1 < n) {
        row_ptr[i0 + 1] = excl + c0;
        cursor[i0 + 1]  = excl + c0;
        dinv[i0 + 1]    = rsqrtf((float)(c1 + 1));
    }
}

__global__ void fill_kernel(const int* __restrict__ src, const int* __restrict__ dst,
                            int* __restrict__ cursor, const float* __restrict__ dinv,
                            int* __restrict__ csr_src, float* __restrict__ csr_wt, int E) {
    int i = (blockIdx.x * blockDim.x + threadIdx.x) * 2;
    if (i + 1 < E) {
        int2 s2 = *(const int2*)(src + i);
        int2 d2 = *(const int2*)(dst + i);
        int p0 = atomicAdd(&cursor[d2.x], 1);
        int p1 = atomicAdd(&cursor[d2.y], 1);
        csr_src[p0] = s2.x;
        csr_src[p1] = s2.y;
        csr_wt[p0]  = dinv[s2.x] * dinv[d2.x];
        csr_wt[p1]  = dinv[s2.y] * dinv[d2.y];
    } else if (i < E) {
        int s = src[i], d = dst[i];
        int pos = atomicAdd(&cursor[d], 1);
        csr_src[pos] = s;
        csr_wt[pos]  = dinv[s] * dinv[d];
    }
}

// W[k][ncols] fp32 -> Wt_h/Wt_l[col][k] bf16 hi/lo (transposed, split). Tiny, once.
__global__ __launch_bounds__(256) void wsplit_kernel(const float* __restrict__ W,
                                                     ushort* __restrict__ th,
                                                     ushort* __restrict__ tl, int ncols) {
    int idx = blockIdx.x * 256 + threadIdx.x;   // over 128*ncols
    if (idx >= 128 * ncols) return;
    int col = idx >> 7;
    int k   = idx & 127;
    float v = W[(size_t)k * ncols + col];
    ushort h = f2bf(v);
    th[idx] = h;
    tl[idx] = f2bf(v - bf2f(h));
}

// agg: out_{h,l}[node,f] = split( dinv^2*feat[node,f] + sum_e wt[e]*feat[src[e],f] )
// one wave per node; two 32-lane groups own alternate edges; 4 gathers in flight.
__global__ __launch_bounds__(256) void agg_kernel(const float* __restrict__ feat,
                                                  const int* __restrict__ row_ptr,
                                                  const int* __restrict__ csr_src,
                                                  const float* __restrict__ csr_wt,
                                                  const float* __restrict__ dinv,
                                                  ushort* __restrict__ outh,
                                                  ushort* __restrict__ outl, int n) {
    const int w    = threadIdx.x >> 6;         // wave 0..3
    const int lane = threadIdx.x & 63;
    const int node = blockIdx.x * 4 + w;
    if (node >= n) return;
    const int g = lane >> 5;                   // edge-parity group 0/1
    const int c = lane & 31;                   // float4 column index (covers 128 feats)

    float di = dinv[node];
    float4 acc = make_float4(0.f, 0.f, 0.f, 0.f);
    if (g == 0) {                              // self-loop message
        float4 v = ((const float4*)(feat + (size_t)node * 128))[c];
        float s2 = di * di;
        acc.x = v.x * s2; acc.y = v.y * s2; acc.z = v.z * s2; acc.w = v.w * s2;
    }

    int e0 = row_ptr[node], e1 = row_ptr[node + 1];
    int e = e0 + g;
    for (; e + 6 < e1; e += 8) {               // 4 edges per group in flight
        int   s0 = csr_src[e],     s1 = csr_src[e + 2];
        int   s2 = csr_src[e + 4], s3 = csr_src[e + 6];
        float w0 = csr_wt[e],      w1 = csr_wt[e + 2];
        float w2 = csr_wt[e + 4],  w3 = csr_wt[e + 6];
        float4 v0 = ((const float4*)(feat + (size_t)s0 * 128))[c];
        float4 v1 = ((const float4*)(feat + (size_t)s1 * 128))[c];
        float4 v2 = ((const float4*)(feat + (size_t)s2 * 128))[c];
        float4 v3 = ((const float4*)(feat + (size_t)s3 * 128))[c];
        acc.x += v0.x * w0 + v1.x * w1 + v2.x * w2 + v3.x * w3;
        acc.y += v0.y * w0 + v1.y * w1 + v2.y * w2 + v3.y * w3;
        acc.z += v0.z * w0 + v1.z * w1 + v2.z * w2 + v3.z * w3;
        acc.w += v0.w * w0 + v1.w * w1 + v2.w * w2 + v3.w * w3;
    }
    for (; e < e1; e += 2) {
        int   s0 = csr_src[e];
        float w0 = csr_wt[e];
        float4 v0 = ((const float4*)(feat + (size_t)s0 * 128))[c];
        acc.x += v0.x * w0; acc.y += v0.y * w0; acc.z += v0.z * w0; acc.w += v0.w * w0;
    }

    // combine the two edge groups
    acc.x += __shfl_xor(acc.x, 32, 64);
    acc.y += __shfl_xor(acc.y, 32, 64);
    acc.z += __shfl_xor(acc.z, 32, 64);
    acc.w += __shfl_xor(acc.w, 32, 64);

    if (g == 0) {
        ushort4 h, l;
        h.x = f2bf(acc.x); l.x = f2bf(acc.x - bf2f(h.x));
        h.y = f2bf(acc.y); l.y = f2bf(acc.y - bf2f(h.y));
        h.z = f2bf(acc.z); l.z = f2bf(acc.z - bf2f(h.z));
        h.w = f2bf(acc.w); l.w = f2bf(acc.w - bf2f(h.w));
        *(ushort4*)(outh + (size_t)node * 128 + c * 4) = h;
        *(ushort4*)(outl + (size_t)node * 128 + c * 4) = l;
    }
}

// ---------------------------------------------------------------------------
// C[N, 128-col chunk] = X @ W + bias (split-bf16 MFMA), inputs pre-split:
//   Xh/Xl: [N][128] bf16 row-major; Wth/Wtl: [colG][128] bf16 (pre-transposed).
// LDS per half-K: [row|col 0..127][k 0..63] bf16, 16B-chunk XOR swizzle
//   byte ^ ((row&7)<<4), both write and read sides.
// Fragment maps (mfma_f32_16x16x32_bf16):
//   A: row=lane&15, k=(lane>>4)*8+j ; B: col=lane&15, same k
//   C/D: col=lane&15, row=(lane>>4)*4+reg   [guide m89-verified]
// T14: phase-1 globals issued into regs before phase-0 MFMAs.
// ---------------------------------------------------------------------------
__global__ __launch_bounds__(256, 2) void gemm_mfma(const ushort* __restrict__ Xh_g,
                                                    const ushort* __restrict__ Xl_g,
                                                    const ushort* __restrict__ Wth_g,
                                                    const ushort* __restrict__ Wtl_g,
                                                    const float* __restrict__ bias,
                                                    float* __restrict__ C,
                                                    int N, int ldw, int do_relu) {
    __shared__ ushort Xh[128 * 64];   // 16 KB each, 64 KB total -> 2 blocks/CU
    __shared__ ushort Xl[128 * 64];
    __shared__ ushort Wh[128 * 64];
    __shared__ ushort Wl[128 * 64];

    const int tid  = threadIdx.x;
    const int lane = tid & 63;
    const int wv   = tid >> 6;        // wave 0..3
    const int wr   = wv >> 1;         // wave row 0..1 (64 rows each)
    const int wc   = wv & 1;          // wave col 0..1 (64 cols each)
    const int lr   = lane & 15;
    const int lk   = lane >> 4;       // k-group 0..3
    const int row0   = blockIdx.y * 128;
    const int colOff = blockIdx.x * 128;

    // per-thread staging geometry (16B chunks)
    const int srow = tid >> 3;                 // helper row/col base for q=0
    const int skch = tid & 7;

    f32x4 acc[4][4];
#pragma unroll
    for (int i = 0; i < 4; ++i)
#pragma unroll
        for (int j = 0; j < 4; ++j)
            acc[i][j] = (f32x4){0.f, 0.f, 0.f, 0.f};

    // ---- stage phase 0 directly (global -> LDS, swizzled) ----
#pragma unroll
    for (int q = 0; q < 4; ++q) {
        int cidx = tid + 256 * q;
        int row  = cidx >> 3;
        int kch  = cidx & 7;
        int gr   = row0 + row; if (gr >= N) gr = N - 1;
        size_t ge = (size_t)gr * 128 + kch * 8;
        int lb = row * 128 + ((kch * 16) ^ ((row & 7) << 4));
        *(int4*)((char*)Xh + lb) = *(const int4*)(Xh_g + ge);
        *(int4*)((char*)Xl + lb) = *(const int4*)(Xl_g + ge);
        size_t gw = (size_t)(colOff + row) * 128 + kch * 8;
        *(int4*)((char*)Wh + lb) = *(const int4*)(Wth_g + gw);
        *(int4*)((char*)Wl + lb) = *(const int4*)(Wtl_g + gw);
    }
    __syncthreads();

    // ---- issue phase-1 global loads into regs (latency hides under MFMAs) ----
    int4 pxh[4], pxl[4], pwh[4], pwl[4];
#pragma unroll
    for (int q = 0; q < 4; ++q) {
        int cidx = tid + 256 * q;
        int row  = cidx >> 3;
        int kch  = cidx & 7;
        int gr   = row0 + row; if (gr >= N) gr = N - 1;
        size_t ge = (size_t)gr * 128 + 64 + kch * 8;
        pxh[q] = *(const int4*)(Xh_g + ge);
        pxl[q] = *(const int4*)(Xl_g + ge);
        size_t gw = (size_t)(colOff + row) * 128 + 64 + kch * 8;
        pwh[q] = *(const int4*)(Wth_g + gw);
        pwl[q] = *(const int4*)(Wtl_g + gw);
    }

    // ---- compute helper over the resident 64-K tile ----
    auto compute64 = [&]() {
#pragma unroll
        for (int kk = 0; kk < 2; ++kk) {
            const int kb2 = (kk * 32 + lk * 8) * 2;   // byte offset pre-swizzle
            bf16x8 ah[4], al[4], bh[4], bl[4];
#pragma unroll
            for (int mi = 0; mi < 4; ++mi) {
                int row  = wr * 64 + mi * 16 + lr;
                int byte = row * 128 + (kb2 ^ ((row & 7) << 4));
                ah[mi] = *(const bf16x8*)((const char*)Xh + byte);
                al[mi] = *(const bf16x8*)((const char*)Xl + byte);
            }
#pragma unroll
            for (int ni = 0; ni < 4; ++ni) {
                int col  = wc * 64 + ni * 16 + lr;
                int byte = col * 128 + (kb2 ^ ((col & 7) << 4));
                bh[ni] = *(const bf16x8*)((const char*)Wh + byte);
                bl[ni] = *(const bf16x8*)((const char*)Wl + byte);
            }
#pragma unroll
            for (int mi = 0; mi < 4; ++mi)
#pragma unroll
                for (int ni = 0; ni < 4; ++ni) {
                    acc[mi][ni] = __builtin_amdgcn_mfma_f32_16x16x32_bf16(
                        ah[mi], bh[ni], acc[mi][ni], 0, 0, 0);
                    acc[mi][ni] = __builtin_amdgcn_mfma_f32_16x16x32_bf16(
                        ah[mi], bl[ni], acc[mi][ni], 0, 0, 0);
                    acc[mi][ni] = __builtin_amdgcn_mfma_f32_16x16x32_bf16(
                        al[mi], bh[ni], acc[mi][ni], 0, 0, 0);
                }
        }
    };

    compute64();                       // phase 0
    __syncthreads();                   // everyone done reading phase-0 LDS

    // ---- write prefetched phase-1 data to LDS ----
#pragma unroll
    for (int q = 0; q < 4; ++q) {
        int cidx = tid + 256 * q;
        int row  = cidx >> 3;
        int kch  = cidx & 7;
        int lb = row * 128 + ((kch * 16) ^ ((row & 7) << 4));
        *(int4*)((char*)Xh + lb) = pxh[q];
        *(int4*)((char*)Xl + lb) = pxl[q];
        *(int4*)((char*)Wh + lb) = pwh[q];
        *(int4*)((char*)Wl + lb) = pwl[q];
    }
    __syncthreads();

    compute64();                       // phase 1
    (void)srow; (void)skch;

    // ---- epilogue: bias (+relu), scalar stores (64B/quarter-wave segments) ----
#pragma unroll
    for (int ni = 0; ni < 4; ++ni) {
        int col = colOff + wc * 64 + ni * 16 + lr;
        float bv = bias[col];
#pragma unroll
        for (int mi = 0; mi < 4; ++mi) {
            int rbase = row0 + wr * 64 + mi * 16 + (lane >> 4) * 4;
#pragma unroll
            for (int r = 0; r < 4; ++r) {
                int row = rbase + r;
                if (row < N) {
                    float v = acc[mi][ni][r] + bv;
                    if (do_relu) v = fmaxf(v, 0.f);
                    C[(size_t)row * ldw + col] = v;
                }
            }
        }
    }
}

// one wave per query edge; 4 lane-groups of 16 gather the 4 head-vectors in
// ONE float4 issue; shfl_xor(16) pairs er*ec; 16-lane reduce; shfl_xor(32)
// marries pi (lanes 0..31) with pj (lanes 32..63).
__global__ __launch_bounds__(256) void query_kernel(const float* __restrict__ emb,
                                                    const int* __restrict__ qrow,
                                                    const int* __restrict__ qcol,
                                                    const int* __restrict__ y,
                                                    float* __restrict__ pred_i,
                                                    float* __restrict__ pred_j,
                                                    float* __restrict__ pred, int Q) {
    int wave = (int)((blockIdx.x * 256 + threadIdx.x) >> 6);
    int lane = threadIdx.x & 63;
    if (wave >= Q) return;
    int r = qrow[wave], c = qcol[wave];
    int yr = y[r], yc = y[c];                  // uniform -> broadcast loads
    int g = lane >> 4;                         // 0: emb[r,yr] 1: emb[c,yr] 2: emb[r,yc] 3: emb[c,yc]
    int t = lane & 15;
    int node = (g & 1) ? c : r;
    int head = (g >> 1) ? yc : yr;
    const float4* p = (const float4*)(emb + (size_t)node * 512 + head * 64);
    float4 v = p[t];
    float4 o;
    o.x = __shfl_xor(v.x, 16, 64);
    o.y = __shfl_xor(v.y, 16, 64);
    o.z = __shfl_xor(v.z, 16, 64);
    o.w = __shfl_xor(v.w, 16, 64);
    float s = v.x * o.x + v.y * o.y + v.z * o.z + v.w * o.w;
#pragma unroll
    for (int off = 8; off >= 1; off >>= 1) s += __shfl_xor(s, off, 64);
    float other = __shfl_xor(s, 32, 64);       // lane0: pj
    if (lane == 0) {
        pred_i[wave] = s;
        pred_j[wave] = other;
        pred[wave]   = 0.5f * (s + other);
    }
}

extern "C" void kernel_launch(void* const* d_in, const int* in_sizes, int n_in,
                              void* d_out, int out_size, void* d_ws, size_t ws_size,
                              hipStream_t stream) {
    const float* x   = (const float*)d_in[0];
    const float* W1  = (const float*)d_in[1];
    const float* b1  = (const float*)d_in[2];
    const float* W2  = (const float*)d_in[3];
    const float* b2  = (const float*)d_in[4];
    const int* edge  = (const int*)d_in[5];
    const int* qedge = (const int*)d_in[6];
    const int* y     = (const int*)d_in[7];

    const int N = in_sizes[0] / 128;   // 100000
    const int E = in_sizes[5] / 2;     // 1600000
    const int Q = in_sizes[6] / 2;     // 400000

    float* out     = (float*)d_out;
    float* hiddens = out;                         // [N,128]
    float* emb     = out + (size_t)N * 128;       // [N,512]
    float* pred_i  = emb + (size_t)N * 512;       // [Q]
    float* pred_j  = pred_i + Q;                  // [Q]
    float* pred    = pred_j + Q;                  // [Q]

    // workspace carve (256B aligned)
    char* w = (char*)d_ws;
    auto alloc = [&](size_t bytes) { char* p = w; w += (bytes + 255) & ~(size_t)255; return p; };
    int*    cnt      = (int*)alloc((size_t)N * 4);
    int*    row_ptr  = (int*)alloc((size_t)(N + 1) * 4);
    int*    cursor   = (int*)alloc((size_t)N * 4);
    float*  dinv     = (float*)alloc((size_t)N * 4);
    int*    csr_src  = (int*)alloc((size_t)E * 4);
    float*  csr_wt   = (float*)alloc((size_t)E * 4);
    int*    blocksum = (int*)alloc(256 * 4);
    int*    blockoff = (int*)alloc(256 * 4);
    ushort* aggh     = (ushort*)alloc((size_t)N * 128 * 2);   // 25.6 MB
    ushort* aggl     = (ushort*)alloc((size_t)N * 128 * 2);   // 25.6 MB
    ushort* w1h      = (ushort*)alloc(128 * 128 * 2);
    ushort* w1l      = (ushort*)alloc(128 * 128 * 2);
    ushort* w2h      = (ushort*)alloc(128 * 512 * 2);
    ushort* w2l      = (ushort*)alloc(128 * 512 * 2);

    const int* esrc = edge;         const int* edst = edge + E;
    const int* qrow = qedge;        const int* qcol = qedge + Q;

    const int nb = (N + SCAN_SEG - 1) / SCAN_SEG;   // 196 <= 256

    hipMemsetAsync(cnt, 0, (size_t)N * 4, stream);
    count_kernel<<<dim3((E / 4 + 255) / 256), dim3(256), 0, stream>>>(edst, cnt, E);
    blocksum_kernel<<<dim3(nb), dim3(256), 0, stream>>>(cnt, blocksum, N);
    blockscan_kernel<<<dim3(1), dim3(256), 0, stream>>>(blocksum, blockoff, nb, row_ptr, N, E);
    csr_ptr_kernel<<<dim3(nb), dim3(256), 0, stream>>>(cnt, blockoff, row_ptr, cursor, dinv, N);
    fill_kernel<<<dim3((E / 2 + 255) / 256), dim3(256), 0, stream>>>(esrc, edst, cursor, dinv, csr_src, csr_wt, E);

    // one-time weight transpose+split (tiny)
    wsplit_kernel<<<dim3((128 * 128 + 255) / 256), dim3(256), 0, stream>>>(W1, w1h, w1l, 128);
    wsplit_kernel<<<dim3((128 * 512 + 255) / 256), dim3(256), 0, stream>>>(W2, w2h, w2l, 512);

    const int mblocks = (N + 127) / 128;   // 782
    const int ablocks = (N + 3) / 4;       // 25000

    // layer 1: aggregate x (split output), then MFMA GEMM with fused bias+relu
    agg_kernel<<<dim3(ablocks), dim3(256), 0, stream>>>(x, row_ptr, csr_src, csr_wt, dinv, aggh, aggl, N);
    gemm_mfma<<<dim3(1, mblocks), dim3(256), 0, stream>>>(aggh, aggl, w1h, w1l, b1, hiddens, N, 128, 1);

    // layer 2: aggregate hiddens, then MFMA GEMM with fused bias
    agg_kernel<<<dim3(ablocks), dim3(256), 0, stream>>>(hiddens, row_ptr, csr_src, csr_wt, dinv, aggh, aggl, N);
    gemm_mfma<<<dim3(4, mblocks), dim3(256), 0, stream>>>(aggh, aggl, w2h, w2l, b2, emb, N, 512, 0);

    query_kernel<<<dim3((Q + 3) / 4), dim3(256), 0, stream>>>(emb, qrow, qcol, y, pred_i, pred_j, pred, Q);
}

// Round 5
// 916.195 us; speedup vs baseline: 1.1295x; 1.1295x over previous
//
#include <hip/hip_runtime.h>
#include <hip/hip_bf16.h>

// ---------------------------------------------------------------------------
// GNN: hiddens = relu(gcn(x,W1,b1)); emb = gcn(hiddens,W2,b2);
// pred_i/j = <emb[r,y,:],emb[c,y,:]> at head y[r]/y[c].
//
// aggregate-then-transform: A_norm @ (H @ W) = (A_norm @ H) @ W.
// CSR build: count -> 3-phase scan -> fill writes PAIRED {src, wt} int2
//   (one 8B scattered store/edge instead of two 4B stores to two arrays).
// agg: wave/node, 2x32-lane edge groups, float4 gathers 4-deep in flight,
//      writes bf16 hi/lo (split hoisted out of GEMM).
// GEMM: split-bf16 MFMA (C = Ah*Bh + Ah*Bl + Al*Bh, fp32 accumulate).
//   128x128 tile, 4 waves (2x2), wave tile 64x64 = 4x4 frags of 16x16x32.
//   BK=64 x 2 phases, 64KB LDS -> 2 blocks/CU. (Round-4 T14 prefetch
//   REVERTED: 64 extra live VGPRs across the MFMA block risked spill.)
// ---------------------------------------------------------------------------

#define SCAN_SEG 512   // elements per scan block (256 threads x 2)

typedef short bf16x8 __attribute__((ext_vector_type(8)));   // 8 bf16 in 4 VGPRs
typedef float f32x4  __attribute__((ext_vector_type(4)));

__device__ __forceinline__ ushort f2bf(float x) {           // truncate: lo term catches residual
    return (ushort)(__float_as_uint(x) >> 16);
}
__device__ __forceinline__ float bf2f(ushort h) {
    return __uint_as_float(((unsigned)h) << 16);
}

__global__ void count_kernel(const int* __restrict__ dst, int* __restrict__ cnt, int E) {
    int e = blockIdx.x * blockDim.x + threadIdx.x;
    if (e < E) atomicAdd(&cnt[dst[e]], 1);
}

// phase 1: per-block segment sums (coalesced)
__global__ __launch_bounds__(256) void blocksum_kernel(const int* __restrict__ cnt,
                                                       int* __restrict__ blocksum, int n) {
    __shared__ int red[4];
    int b = blockIdx.x, t = threadIdx.x;
    int i0 = b * SCAN_SEG + t;
    int s = 0;
    if (i0 < n) s += cnt[i0];
    if (i0 + 256 < n) s += cnt[i0 + 256];
#pragma unroll
    for (int off = 32; off >= 1; off >>= 1) s += __shfl_xor(s, off, 64);
    if ((t & 63) == 0) red[t >> 6] = s;
    __syncthreads();
    if (t == 0) blocksum[b] = red[0] + red[1] + red[2] + red[3];
}

// phase 2: exclusive scan of <=256 block sums in one small block
__global__ __launch_bounds__(256) void blockscan_kernel(const int* __restrict__ blocksum,
                                                        int* __restrict__ blockoff, int nb,
                                                        int* __restrict__ row_ptr, int n, int E) {
    __shared__ int s[256];
    int t = threadIdx.x;
    int v = (t < nb) ? blocksum[t] : 0;
    s[t] = v;
    __syncthreads();
    for (int off = 1; off < 256; off <<= 1) {
        int u = (t >= off) ? s[t - off] : 0;
        __syncthreads();
        s[t] += u;
        __syncthreads();
    }
    if (t < nb) blockoff[t] = s[t] - v;   // exclusive
    if (t == 0) row_ptr[n] = E;
}

// phase 3: per-block exclusive scan over its 512-elem segment -> row_ptr/cursor/dinv
__global__ __launch_bounds__(256) void csr_ptr_kernel(const int* __restrict__ cnt,
                                                      const int* __restrict__ blockoff,
                                                      int* __restrict__ row_ptr,
                                                      int* __restrict__ cursor,
                                                      float* __restrict__ dinv, int n) {
    __shared__ int s[256];
    int b = blockIdx.x, t = threadIdx.x;
    int i0 = b * SCAN_SEG + 2 * t;       // thread handles i0, i0+1
    int c0 = (i0     < n) ? cnt[i0]     : 0;
    int c1 = (i0 + 1 < n) ? cnt[i0 + 1] : 0;
    int pair = c0 + c1;
    s[t] = pair;
    __syncthreads();
    for (int off = 1; off < 256; off <<= 1) {
        int u = (t >= off) ? s[t - off] : 0;
        __syncthreads();
        s[t] += u;
        __syncthreads();
    }
    int excl = s[t] - pair + blockoff[b];
    if (i0 < n) {
        row_ptr[i0] = excl;
        cursor[i0]  = excl;
        dinv[i0]    = rsqrtf((float)(c0 + 1));
    }
    if (i0 + 1 < n) {
        row_ptr[i0 + 1] = excl + c0;
        cursor[i0 + 1]  = excl + c0;
        dinv[i0 + 1]    = rsqrtf((float)(c1 + 1));
    }
}

// fill PAIRED csr entries: one 8B store per edge (halves write-allocate lines)
__global__ void fill_kernel(const int* __restrict__ src, const int* __restrict__ dst,
                            int* __restrict__ cursor, const float* __restrict__ dinv,
                            int2* __restrict__ csr, int E) {
    int e = blockIdx.x * blockDim.x + threadIdx.x;
    if (e < E) {
        int s = src[e], d = dst[e];
        int pos = atomicAdd(&cursor[d], 1);
        csr[pos] = make_int2(s, __float_as_int(dinv[s] * dinv[d]));
    }
}

// W[k][ncols] fp32 -> Wt_h/Wt_l[col][k] bf16 hi/lo (transposed, split). Tiny, once.
__global__ __launch_bounds__(256) void wsplit_kernel(const float* __restrict__ W,
                                                     ushort* __restrict__ th,
                                                     ushort* __restrict__ tl, int ncols) {
    int idx = blockIdx.x * 256 + threadIdx.x;   // over 128*ncols
    if (idx >= 128 * ncols) return;
    int col = idx >> 7;
    int k   = idx & 127;
    float v = W[(size_t)k * ncols + col];
    ushort h = f2bf(v);
    th[idx] = h;
    tl[idx] = f2bf(v - bf2f(h));
}

// agg: out_{h,l}[node,f] = split( dinv^2*feat[node,f] + sum_e wt[e]*feat[src[e],f] )
// one wave per node; two 32-lane groups own alternate edges; 4 gathers in flight.
__global__ __launch_bounds__(256) void agg_kernel(const float* __restrict__ feat,
                                                  const int* __restrict__ row_ptr,
                                                  const int2* __restrict__ csr,
                                                  const float* __restrict__ dinv,
                                                  ushort* __restrict__ outh,
                                                  ushort* __restrict__ outl, int n) {
    const int w    = threadIdx.x >> 6;         // wave 0..3
    const int lane = threadIdx.x & 63;
    const int node = blockIdx.x * 4 + w;
    if (node >= n) return;
    const int g = lane >> 5;                   // edge-parity group 0/1
    const int c = lane & 31;                   // float4 column index (covers 128 feats)

    float di = dinv[node];
    float4 acc = make_float4(0.f, 0.f, 0.f, 0.f);
    if (g == 0) {                              // self-loop message
        float4 v = ((const float4*)(feat + (size_t)node * 128))[c];
        float s2 = di * di;
        acc.x = v.x * s2; acc.y = v.y * s2; acc.z = v.z * s2; acc.w = v.w * s2;
    }

    int e0 = row_ptr[node], e1 = row_ptr[node + 1];
    int e = e0 + g;
    for (; e + 6 < e1; e += 8) {               // 4 edges per group in flight
        int2 p0 = csr[e],     p1 = csr[e + 2];
        int2 p2 = csr[e + 4], p3 = csr[e + 6];
        float w0 = __int_as_float(p0.y), w1 = __int_as_float(p1.y);
        float w2 = __int_as_float(p2.y), w3 = __int_as_float(p3.y);
        float4 v0 = ((const float4*)(feat + (size_t)p0.x * 128))[c];
        float4 v1 = ((const float4*)(feat + (size_t)p1.x * 128))[c];
        float4 v2 = ((const float4*)(feat + (size_t)p2.x * 128))[c];
        float4 v3 = ((const float4*)(feat + (size_t)p3.x * 128))[c];
        acc.x += v0.x * w0 + v1.x * w1 + v2.x * w2 + v3.x * w3;
        acc.y += v0.y * w0 + v1.y * w1 + v2.y * w2 + v3.y * w3;
        acc.z += v0.z * w0 + v1.z * w1 + v2.z * w2 + v3.z * w3;
        acc.w += v0.w * w0 + v1.w * w1 + v2.w * w2 + v3.w * w3;
    }
    for (; e < e1; e += 2) {
        int2 p0 = csr[e];
        float w0 = __int_as_float(p0.y);
        float4 v0 = ((const float4*)(feat + (size_t)p0.x * 128))[c];
        acc.x += v0.x * w0; acc.y += v0.y * w0; acc.z += v0.z * w0; acc.w += v0.w * w0;
    }

    // combine the two edge groups
    acc.x += __shfl_xor(acc.x, 32, 64);
    acc.y += __shfl_xor(acc.y, 32, 64);
    acc.z += __shfl_xor(acc.z, 32, 64);
    acc.w += __shfl_xor(acc.w, 32, 64);

    if (g == 0) {
        ushort4 h, l;
        h.x = f2bf(acc.x); l.x = f2bf(acc.x - bf2f(h.x));
        h.y = f2bf(acc.y); l.y = f2bf(acc.y - bf2f(h.y));
        h.z = f2bf(acc.z); l.z = f2bf(acc.z - bf2f(h.z));
        h.w = f2bf(acc.w); l.w = f2bf(acc.w - bf2f(h.w));
        *(ushort4*)(outh + (size_t)node * 128 + c * 4) = h;
        *(ushort4*)(outl + (size_t)node * 128 + c * 4) = l;
    }
}

// ---------------------------------------------------------------------------
// C[N, 128-col chunk] = X @ W + bias (split-bf16 MFMA), inputs pre-split:
//   Xh/Xl: [N][128] bf16 row-major; Wth/Wtl: [colG][128] bf16 (pre-transposed).
// LDS per half-K: [row|col 0..127][k 0..63] bf16, 16B-chunk XOR swizzle
//   byte ^ ((row&7)<<4), both write and read sides.
// Fragment maps (mfma_f32_16x16x32_bf16):
//   A: row=lane&15, k=(lane>>4)*8+j ; B: col=lane&15, same k
//   C/D: col=lane&15, row=(lane>>4)*4+reg   [guide m89-verified]
// ---------------------------------------------------------------------------
__global__ __launch_bounds__(256, 2) void gemm_mfma(const ushort* __restrict__ Xh_g,
                                                    const ushort* __restrict__ Xl_g,
                                                    const ushort* __restrict__ Wth_g,
                                                    const ushort* __restrict__ Wtl_g,
                                                    const float* __restrict__ bias,
                                                    float* __restrict__ C,
                                                    int N, int ldw, int do_relu) {
    __shared__ ushort Xh[128 * 64];   // 16 KB each, 64 KB total -> 2 blocks/CU
    __shared__ ushort Xl[128 * 64];
    __shared__ ushort Wh[128 * 64];
    __shared__ ushort Wl[128 * 64];

    const int tid  = threadIdx.x;
    const int lane = tid & 63;
    const int wv   = tid >> 6;        // wave 0..3
    const int wr   = wv >> 1;         // wave row 0..1 (64 rows each)
    const int wc   = wv & 1;          // wave col 0..1 (64 cols each)
    const int lr   = lane & 15;
    const int lk   = lane >> 4;       // k-group 0..3
    const int row0   = blockIdx.y * 128;
    const int colOff = blockIdx.x * 128;

    f32x4 acc[4][4];
#pragma unroll
    for (int i = 0; i < 4; ++i)
#pragma unroll
        for (int j = 0; j < 4; ++j)
            acc[i][j] = (f32x4){0.f, 0.f, 0.f, 0.f};

    for (int ph = 0; ph < 2; ++ph) {
        if (ph) __syncthreads();      // prev compute done before overwrite

        // ---- stage X half-tile: pure swizzled 16B copies ----
#pragma unroll
        for (int q = 0; q < 4; ++q) {
            int cidx = tid + 256 * q;            // 16B-chunk id 0..1023
            int row  = cidx >> 3;                // 0..127
            int kch  = cidx & 7;                 // 16B chunk within 64-k half
            int gr   = row0 + row; if (gr >= N) gr = N - 1;
            size_t ge = (size_t)gr * 128 + ph * 64 + kch * 8;
            int lb = row * 128 + ((kch * 16) ^ ((row & 7) << 4));
            *(int4*)((char*)Xh + lb) = *(const int4*)(Xh_g + ge);
            *(int4*)((char*)Xl + lb) = *(const int4*)(Xl_g + ge);
        }
        // ---- stage W half-tile (already transposed/split in global) ----
#pragma unroll
        for (int q = 0; q < 4; ++q) {
            int cidx = tid + 256 * q;
            int col  = cidx >> 3;
            int kch  = cidx & 7;
            size_t ge = (size_t)(colOff + col) * 128 + ph * 64 + kch * 8;
            int lb = col * 128 + ((kch * 16) ^ ((col & 7) << 4));
            *(int4*)((char*)Wh + lb) = *(const int4*)(Wth_g + ge);
            *(int4*)((char*)Wl + lb) = *(const int4*)(Wtl_g + ge);
        }
        __syncthreads();

        // ---- compute: 2 x K=32 chunks per phase ----
#pragma unroll
        for (int kk = 0; kk < 2; ++kk) {
            const int kb2 = (kk * 32 + lk * 8) * 2;   // byte offset pre-swizzle
            bf16x8 ah[4], al[4], bh[4], bl[4];
#pragma unroll
            for (int mi = 0; mi < 4; ++mi) {
                int row  = wr * 64 + mi * 16 + lr;
                int byte = row * 128 + (kb2 ^ ((row & 7) << 4));
                ah[mi] = *(const bf16x8*)((const char*)Xh + byte);
                al[mi] = *(const bf16x8*)((const char*)Xl + byte);
            }
#pragma unroll
            for (int ni = 0; ni < 4; ++ni) {
                int col  = wc * 64 + ni * 16 + lr;
                int byte = col * 128 + (kb2 ^ ((col & 7) << 4));
                bh[ni] = *(const bf16x8*)((const char*)Wh + byte);
                bl[ni] = *(const bf16x8*)((const char*)Wl + byte);
            }
#pragma unroll
            for (int mi = 0; mi < 4; ++mi)
#pragma unroll
                for (int ni = 0; ni < 4; ++ni) {
                    acc[mi][ni] = __builtin_amdgcn_mfma_f32_16x16x32_bf16(
                        ah[mi], bh[ni], acc[mi][ni], 0, 0, 0);
                    acc[mi][ni] = __builtin_amdgcn_mfma_f32_16x16x32_bf16(
                        ah[mi], bl[ni], acc[mi][ni], 0, 0, 0);
                    acc[mi][ni] = __builtin_amdgcn_mfma_f32_16x16x32_bf16(
                        al[mi], bh[ni], acc[mi][ni], 0, 0, 0);
                }
        }
    }

    // ---- epilogue: bias (+relu), scalar stores (64B/quarter-wave segments) ----
#pragma unroll
    for (int ni = 0; ni < 4; ++ni) {
        int col = colOff + wc * 64 + ni * 16 + lr;
        float bv = bias[col];
#pragma unroll
        for (int mi = 0; mi < 4; ++mi) {
            int rbase = row0 + wr * 64 + mi * 16 + (lane >> 4) * 4;
#pragma unroll
            for (int r = 0; r < 4; ++r) {
                int row = rbase + r;
                if (row < N) {
                    float v = acc[mi][ni][r] + bv;
                    if (do_relu) v = fmaxf(v, 0.f);
                    C[(size_t)row * ldw + col] = v;
                }
            }
        }
    }
}

// one wave per query edge; 4 lane-groups of 16 gather the 4 head-vectors in
// ONE float4 issue; shfl_xor(16) pairs er*ec; 16-lane reduce; shfl_xor(32)
// marries pi (lanes 0..31) with pj (lanes 32..63).
__global__ __launch_bounds__(256) void query_kernel(const float* __restrict__ emb,
                                                    const int* __restrict__ qrow,
                                                    const int* __restrict__ qcol,
                                                    const int* __restrict__ y,
                                                    float* __restrict__ pred_i,
                                                    float* __restrict__ pred_j,
                                                    float* __restrict__ pred, int Q) {
    int wave = (int)((blockIdx.x * 256 + threadIdx.x) >> 6);
    int lane = threadIdx.x & 63;
    if (wave >= Q) return;
    int r = qrow[wave], c = qcol[wave];
    int yr = y[r], yc = y[c];                  // uniform -> broadcast loads
    int g = lane >> 4;                         // 0: emb[r,yr] 1: emb[c,yr] 2: emb[r,yc] 3: emb[c,yc]
    int t = lane & 15;
    int node = (g & 1) ? c : r;
    int head = (g >> 1) ? yc : yr;
    const float4* p = (const float4*)(emb + (size_t)node * 512 + head * 64);
    float4 v = p[t];
    float4 o;
    o.x = __shfl_xor(v.x, 16, 64);
    o.y = __shfl_xor(v.y, 16, 64);
    o.z = __shfl_xor(v.z, 16, 64);
    o.w = __shfl_xor(v.w, 16, 64);
    float s = v.x * o.x + v.y * o.y + v.z * o.z + v.w * o.w;
#pragma unroll
    for (int off = 8; off >= 1; off >>= 1) s += __shfl_xor(s, off, 64);
    float other = __shfl_xor(s, 32, 64);       // lane0: pj
    if (lane == 0) {
        pred_i[wave] = s;
        pred_j[wave] = other;
        pred[wave]   = 0.5f * (s + other);
    }
}

extern "C" void kernel_launch(void* const* d_in, const int* in_sizes, int n_in,
                              void* d_out, int out_size, void* d_ws, size_t ws_size,
                              hipStream_t stream) {
    const float* x   = (const float*)d_in[0];
    const float* W1  = (const float*)d_in[1];
    const float* b1  = (const float*)d_in[2];
    const float* W2  = (const float*)d_in[3];
    const float* b2  = (const float*)d_in[4];
    const int* edge  = (const int*)d_in[5];
    const int* qedge = (const int*)d_in[6];
    const int* y     = (const int*)d_in[7];

    const int N = in_sizes[0] / 128;   // 100000
    const int E = in_sizes[5] / 2;     // 1600000
    const int Q = in_sizes[6] / 2;     // 400000

    float* out     = (float*)d_out;
    float* hiddens = out;                         // [N,128]
    float* emb     = out + (size_t)N * 128;       // [N,512]
    float* pred_i  = emb + (size_t)N * 512;       // [Q]
    float* pred_j  = pred_i + Q;                  // [Q]
    float* pred    = pred_j + Q;                  // [Q]

    // workspace carve (256B aligned)
    char* w = (char*)d_ws;
    auto alloc = [&](size_t bytes) { char* p = w; w += (bytes + 255) & ~(size_t)255; return p; };
    int*    cnt      = (int*)alloc((size_t)N * 4);
    int*    row_ptr  = (int*)alloc((size_t)(N + 1) * 4);
    int*    cursor   = (int*)alloc((size_t)N * 4);
    float*  dinv     = (float*)alloc((size_t)N * 4);
    int2*   csr      = (int2*)alloc((size_t)E * 8);           // paired {src, wt}
    int*    blocksum = (int*)alloc(256 * 4);
    int*    blockoff = (int*)alloc(256 * 4);
    ushort* aggh     = (ushort*)alloc((size_t)N * 128 * 2);   // 25.6 MB
    ushort* aggl     = (ushort*)alloc((size_t)N * 128 * 2);   // 25.6 MB
    ushort* w1h      = (ushort*)alloc(128 * 128 * 2);
    ushort* w1l      = (ushort*)alloc(128 * 128 * 2);
    ushort* w2h      = (ushort*)alloc(128 * 512 * 2);
    ushort* w2l      = (ushort*)alloc(128 * 512 * 2);

    const int* esrc = edge;         const int* edst = edge + E;
    const int* qrow = qedge;        const int* qcol = qedge + Q;

    const int nb = (N + SCAN_SEG - 1) / SCAN_SEG;   // 196 <= 256

    hipMemsetAsync(cnt, 0, (size_t)N * 4, stream);
    count_kernel<<<dim3((E + 255) / 256), dim3(256), 0, stream>>>(edst, cnt, E);
    blocksum_kernel<<<dim3(nb), dim3(256), 0, stream>>>(cnt, blocksum, N);
    blockscan_kernel<<<dim3(1), dim3(256), 0, stream>>>(blocksum, blockoff, nb, row_ptr, N, E);
    csr_ptr_kernel<<<dim3(nb), dim3(256), 0, stream>>>(cnt, blockoff, row_ptr, cursor, dinv, N);
    fill_kernel<<<dim3((E + 255) / 256), dim3(256), 0, stream>>>(esrc, edst, cursor, dinv, csr, E);

    // one-time weight transpose+split (tiny)
    wsplit_kernel<<<dim3((128 * 128 + 255) / 256), dim3(256), 0, stream>>>(W1, w1h, w1l, 128);
    wsplit_kernel<<<dim3((128 * 512 + 255) / 256), dim3(256), 0, stream>>>(W2, w2h, w2l, 512);

    const int mblocks = (N + 127) / 128;   // 782
    const int ablocks = (N + 3) / 4;       // 25000

    // layer 1: aggregate x (split output), then MFMA GEMM with fused bias+relu
    agg_kernel<<<dim3(ablocks), dim3(256), 0, stream>>>(x, row_ptr, csr, dinv, aggh, aggl, N);
    gemm_mfma<<<dim3(1, mblocks), dim3(256), 0, stream>>>(aggh, aggl, w1h, w1l, b1, hiddens, N, 128, 1);

    // layer 2: aggregate hiddens, then MFMA GEMM with fused bias
    agg_kernel<<<dim3(ablocks), dim3(256), 0, stream>>>(hiddens, row_ptr, csr, dinv, aggh, aggl, N);
    gemm_mfma<<<dim3(4, mblocks), dim3(256), 0, stream>>>(aggh, aggl, w2h, w2l, b2, emb, N, 512, 0);

    query_kernel<<<dim3((Q + 3) / 4), dim3(256), 0, stream>>>(emb, qrow, qcol, y, pred_i, pred_j, pred, Q);
}